// Round 1
// baseline (546.447 us; speedup 1.0000x reference)
//
#include <hip/hip_runtime.h>

// Fastfood transform: out = (1/n) * H (G .* P( H (B .* x) ))  per row,
// n = 16384, 4096 rows, fp32.  H = unnormalized Walsh-Hadamard; both 1/sqrt(n)
// factors folded into one 1/n at the end (linear).
//
// One block (256 threads) per row. Row bits: i = [a(4)|b(4)|ch(4)|cl(2)].
// Each thread holds 16 float4s (64 elems). FWHT = 3 register passes
// (bits 0-5, 6-9, 10-13) with 2 XOR-swizzled LDS transposes in between.

#define L_N 16384

__device__ __forceinline__ float4 f4add(float4 a, float4 b) {
    return make_float4(a.x + b.x, a.y + b.y, a.z + b.z, a.w + b.w);
}
__device__ __forceinline__ float4 f4sub(float4 a, float4 b) {
    return make_float4(a.x - b.x, a.y - b.y, a.z - b.z, a.w - b.w);
}

// FWHT_4 within one float4 (bits 0,1)
__device__ __forceinline__ void fwht4_inner(float4& a) {
    float s0 = a.x + a.y, d0 = a.x - a.y;
    float s1 = a.z + a.w, d1 = a.z - a.w;
    a.x = s0 + s1; a.y = d0 + d1; a.z = s0 - s1; a.w = d0 - d1;
}

// FWHT_16 across the 16 float4 slots (vectorized over the 4 inner lanes)
__device__ __forceinline__ void fwht16_vec(float4 v[16]) {
    #pragma unroll
    for (int s = 1; s < 16; s <<= 1) {
        #pragma unroll
        for (int k = 0; k < 16; ++k) {
            if ((k & s) == 0) {
                float4 a = v[k], b = v[k + s];
                v[k]     = f4add(a, b);
                v[k + s] = f4sub(a, b);
            }
        }
    }
}

__device__ __forceinline__ void fwht64_regs(float4 v[16]) {
    #pragma unroll
    for (int k = 0; k < 16; ++k) fwht4_inner(v[k]);
    fwht16_vec(v);
}

extern "C" __global__ void __launch_bounds__(256, 2)
fastfood_kernel(const float* __restrict__ x,
                const float* __restrict__ Bv,
                const float* __restrict__ Gv,
                const int*   __restrict__ Pi,
                float* __restrict__ out)
{
    __shared__ float4 lds4[L_N / 4];          // 64 KiB, exactly one row
    float* lds = (float*)lds4;

    const int t  = threadIdx.x;
    const int th = t >> 4;                    // high 4 bits of thread id
    const int tl = t & 15;                    // low 4 bits
    const long row = blockIdx.x;

    const float4* x4 = (const float4*)(x + row * (long)L_N);
    float4 v[16];

    // ---- load row, fold in B:  thread t owns elements [t*64, t*64+64) ----
    #pragma unroll
    for (int k = 0; k < 16; ++k) {
        float4 a = x4[t * 16 + k];
        float4 b = ((const float4*)Bv)[t * 16 + k];
        v[k] = make_float4(a.x * b.x, a.y * b.y, a.z * b.z, a.w * b.w);
    }

    // ================= FWHT #1 =================
    // pass 1: bits 0-5 in registers (thread role: (a=th, b=tl))
    fwht64_regs(v);

    // transpose W1: slot(a,b,ch=k) -> t*16 + (k^tl).  8-lane bank grp = (k^b)&7: distinct
    #pragma unroll
    for (int k = 0; k < 16; ++k) lds4[t * 16 + (k ^ tl)] = v[k];
    __syncthreads();
    // R1: thread role (a=th, ch=tl); v[m] = group (a, b=m, ch). bank grp (ch^m)&7: distinct
    #pragma unroll
    for (int m = 0; m < 16; ++m) v[m] = lds4[th * 256 + m * 16 + (tl ^ m)];
    // pass 2: bits 6-9 (b)
    fwht16_vec(v);
    __syncthreads();

    // W2: thread (a=th, ch=tl) writes group (a,b=m,ch) at a*256+m*16+(ch^a). grp (ch^a)&7 distinct
    #pragma unroll
    for (int m = 0; m < 16; ++m) lds4[th * 256 + m * 16 + (tl ^ th)] = v[m];
    __syncthreads();
    // R2: thread role (b=th, ch=tl); v[m] = group (a=m, b, ch). grp (ch^m)&7 distinct
    #pragma unroll
    for (int m = 0; m < 16; ++m) v[m] = lds4[m * 256 + th * 16 + (tl ^ m)];
    // pass 3: bits 10-13 (a)
    fwht16_vec(v);
    __syncthreads();

    // write FWHT#1 result in NATURAL layout for the permutation gather:
    // thread (b=th,ch=tl) holds group (a=m,b,ch) -> slot m*256 + th*16 + tl = m*256 + t
    #pragma unroll
    for (int m = 0; m < 16; ++m) lds4[m * 256 + t] = v[m];
    __syncthreads();

    // ---- permutation + G:  v2[i] = y1[Pi[i]] * G[i], thread t owns i in [t*64, t*64+64) ----
    {
        const int4*   p4 = (const int4*)Pi;
        const float4* g4 = (const float4*)Gv;
        #pragma unroll
        for (int k = 0; k < 16; ++k) {
            int4   p = p4[t * 16 + k];
            float4 g = g4[t * 16 + k];
            v[k] = make_float4(lds[p.x] * g.x, lds[p.y] * g.y,
                               lds[p.z] * g.z, lds[p.w] * g.w);
        }
    }
    __syncthreads();   // WAR: all gather reads done before FWHT#2 writes LDS

    // ================= FWHT #2 =================
    fwht64_regs(v);
    #pragma unroll
    for (int k = 0; k < 16; ++k) lds4[t * 16 + (k ^ tl)] = v[k];
    __syncthreads();
    #pragma unroll
    for (int m = 0; m < 16; ++m) v[m] = lds4[th * 256 + m * 16 + (tl ^ m)];
    fwht16_vec(v);
    __syncthreads();
    #pragma unroll
    for (int m = 0; m < 16; ++m) lds4[th * 256 + m * 16 + (tl ^ th)] = v[m];
    __syncthreads();
    #pragma unroll
    for (int m = 0; m < 16; ++m) v[m] = lds4[m * 256 + th * 16 + (tl ^ m)];
    fwht16_vec(v);

    // ---- store: thread (b=th,ch=tl) holds group (a=m,b,ch) -> float4 index m*256 + t ----
    const float sc = 1.0f / (float)L_N;       // both 1/sqrt(n) factors
    float4* o4 = (float4*)(out + row * (long)L_N);
    #pragma unroll
    for (int m = 0; m < 16; ++m) {
        float4 a = v[m];
        o4[m * 256 + t] = make_float4(a.x * sc, a.y * sc, a.z * sc, a.w * sc);
    }
}

extern "C" void kernel_launch(void* const* d_in, const int* in_sizes, int n_in,
                              void* d_out, int out_size, void* d_ws, size_t ws_size,
                              hipStream_t stream) {
    const float* x  = (const float*)d_in[0];
    const float* B  = (const float*)d_in[1];
    const float* G  = (const float*)d_in[2];
    const int*   Pi = (const int*)d_in[3];
    float* out = (float*)d_out;

    const int rows = in_sizes[0] / L_N;       // 4096
    fastfood_kernel<<<rows, 256, 0, stream>>>(x, B, G, Pi, out);
}

// Round 2
// 460.627 us; speedup vs baseline: 1.1863x; 1.1863x over previous
//
#include <hip/hip_runtime.h>

// Fastfood transform: out = (1/n) * H (G .* P( H (B .* x) )) per row,
// n = 16384, 4096 rows, fp32. Both 1/sqrt(n) folded into one 1/n at the end.
//
// One block (512 threads, 8 waves) per row; 64 KiB LDS = the row; 2 blocks/CU
// -> 16 waves/CU (~45% occupancy) vs 8 waves/CU for the 256-thread version.
//
// Element index bits: i = [A(3)|Bb(3)|C(3)|D(3)|cl(2)], f4 index j = i>>2.
// Thread id t = [tu(3)|tv(3)|tw(3)]. Each thread holds 8 float4 (32 elems).
// FWHT_16384 = pass1 (cl+slots, 5 bits in regs) + 3 LDS transpose rounds of
// 3 bits each. Entry layout: slots=A, thread=[Bb|C|D]; exit: slots=Bb,
// thread=(A,C,D) -> natural/coalesced addr = tu*512 + m*64 + tv*8 + tw.
//
// LDS swizzles (f4 units, bank-group = addr&7; every 8 consecutive lanes must
// hit 8 distinct groups):
//  W1: m*512+tu*64+tv*8+(tw^tv)   grp=tw^tv  (cluster: tw varies)  OK
//  W2: tu*512+tv*64+m*8+(tw^m)    grp=tw^m                          OK
//  W3: tu*512+m*64+tw*8+(tv^tw)   grp=tv^tw                         OK
//  R (all rounds): tu*512+tv*64+tw*8+(m^tw)  grp=m^tw               OK
//  natural W/store: tu*512+m*64+tv*8+tw      grp=tw                 OK

#define L_N 16384

__device__ __forceinline__ float4 f4add(float4 a, float4 b) {
    return make_float4(a.x + b.x, a.y + b.y, a.z + b.z, a.w + b.w);
}
__device__ __forceinline__ float4 f4sub(float4 a, float4 b) {
    return make_float4(a.x - b.x, a.y - b.y, a.z - b.z, a.w - b.w);
}

// FWHT_4 within one float4 (the cl bits)
__device__ __forceinline__ void fwht4_inner(float4& a) {
    float s0 = a.x + a.y, d0 = a.x - a.y;
    float s1 = a.z + a.w, d1 = a.z - a.w;
    a.x = s0 + s1; a.y = d0 + d1; a.z = s0 - s1; a.w = d0 - d1;
}

// FWHT_8 across the 8 float4 slots (vectorized over the 4 inner lanes)
__device__ __forceinline__ void fwht8_vec(float4 v[8]) {
    #pragma unroll
    for (int s = 1; s < 8; s <<= 1) {
        #pragma unroll
        for (int k = 0; k < 8; ++k) {
            if ((k & s) == 0) {
                float4 a = v[k], b = v[k + s];
                v[k]     = f4add(a, b);
                v[k + s] = f4sub(a, b);
            }
        }
    }
}

// Full FWHT_16384 (unnormalized). Entry: r[m] = f4 at j = m*512 + t
// (slots = A bits, thread = [Bb|C|D]). Exit: thread (A=tu,C=tv,D=tw),
// slots m = Bb -> natural f4 index = tu*512 + m*64 + tv*8 + tw.
// No trailing __syncthreads(); caller must sync before reusing lds4.
__device__ __forceinline__ void fwht16384(float4 (&r)[8], float4* lds4,
                                          int tu, int tv, int tw) {
    // pass1: cl (2 bits) + A (3 slot bits)
    #pragma unroll
    for (int k = 0; k < 8; ++k) fwht4_inner(r[k]);
    fwht8_vec(r);

    const int rbase = tu * 512 + tv * 64 + tw * 8;

    // round1: bring D into slots
    #pragma unroll
    for (int m = 0; m < 8; ++m) lds4[m * 512 + tu * 64 + tv * 8 + (tw ^ tv)] = r[m];
    __syncthreads();
    #pragma unroll
    for (int m = 0; m < 8; ++m) r[m] = lds4[rbase + (m ^ tw)];
    fwht8_vec(r);          // D
    __syncthreads();

    // round2: bring C into slots
    #pragma unroll
    for (int m = 0; m < 8; ++m) lds4[tu * 512 + tv * 64 + m * 8 + (tw ^ m)] = r[m];
    __syncthreads();
    #pragma unroll
    for (int m = 0; m < 8; ++m) r[m] = lds4[rbase + (m ^ tw)];
    fwht8_vec(r);          // C
    __syncthreads();

    // round3: bring Bb into slots
    #pragma unroll
    for (int m = 0; m < 8; ++m) lds4[tu * 512 + m * 64 + tw * 8 + (tv ^ tw)] = r[m];
    __syncthreads();
    #pragma unroll
    for (int m = 0; m < 8; ++m) r[m] = lds4[rbase + (m ^ tw)];
    fwht8_vec(r);          // Bb
}

extern "C" __global__ void __launch_bounds__(512, 4)
fastfood_kernel(const float* __restrict__ x,
                const float* __restrict__ Bv,
                const float* __restrict__ Gv,
                const int*   __restrict__ Pi,
                float* __restrict__ out)
{
    __shared__ float4 lds4[L_N / 4];          // 64 KiB, exactly one row
    float* lds = (float*)lds4;

    const int t  = threadIdx.x;
    const int tu = t >> 6, tv = (t >> 3) & 7, tw = t & 7;
    const long row = blockIdx.x;

    const float4* x4 = (const float4*)(x + row * (long)L_N);
    const float4* b4 = (const float4*)Bv;
    float4 r[8];

    // load row (coalesced: per slot, lanes consecutive), fold in B
    #pragma unroll
    for (int m = 0; m < 8; ++m) {
        float4 a = x4[m * 512 + t];
        float4 b = b4[m * 512 + t];
        r[m] = make_float4(a.x * b.x, a.y * b.y, a.z * b.z, a.w * b.w);
    }

    // ================= FWHT #1 =================
    fwht16384(r, lds4, tu, tv, tw);
    __syncthreads();   // WAR: round3 reads done before natural write

    // natural layout write for the permutation gather
    #pragma unroll
    for (int m = 0; m < 8; ++m) lds4[tu * 512 + m * 64 + tv * 8 + tw] = r[m];
    __syncthreads();

    // permutation + G: thread owns f4 index j = k*512 + t  (coalesced Pi/G)
    {
        const int4*   p4 = (const int4*)Pi;
        const float4* g4 = (const float4*)Gv;
        #pragma unroll
        for (int k = 0; k < 8; ++k) {
            int4   p = p4[k * 512 + t];
            float4 g = g4[k * 512 + t];
            r[k] = make_float4(lds[p.x] * g.x, lds[p.y] * g.y,
                               lds[p.z] * g.z, lds[p.w] * g.w);
        }
    }
    __syncthreads();   // WAR: all gather reads done before FWHT#2 writes LDS

    // ================= FWHT #2 ================= (same entry layout: slots=A)
    fwht16384(r, lds4, tu, tv, tw);

    // store, both normalizations folded; coalesced per slot
    const float sc = 1.0f / (float)L_N;
    float4* o4 = (float4*)(out + row * (long)L_N);
    #pragma unroll
    for (int m = 0; m < 8; ++m) {
        float4 a = r[m];
        o4[tu * 512 + m * 64 + tv * 8 + tw] =
            make_float4(a.x * sc, a.y * sc, a.z * sc, a.w * sc);
    }
}

extern "C" void kernel_launch(void* const* d_in, const int* in_sizes, int n_in,
                              void* d_out, int out_size, void* d_ws, size_t ws_size,
                              hipStream_t stream) {
    const float* x  = (const float*)d_in[0];
    const float* B  = (const float*)d_in[1];
    const float* G  = (const float*)d_in[2];
    const int*   Pi = (const int*)d_in[3];
    float* out = (float*)d_out;

    const int rows = in_sizes[0] / L_N;       // 4096
    fastfood_kernel<<<rows, 512, 0, stream>>>(x, B, G, Pi, out);
}